// Round 7
// baseline (100967.645 us; speedup 1.0000x reference)
//
#include <hip/hip_runtime.h>
#include <cstdint>

typedef __bf16 bf16;

// ---------------------------------------------------------------------------
// NAIVE GEMM: out[m][n] = sum_k X[m][k]*W[n][k] + bias[n]. One thread per
// output element, plain fp32 k-loop.
// ---------------------------------------------------------------------------
template <typename TX, typename TOUT>
__global__ __launch_bounds__(256) void gemm_naive(
    const TX* __restrict__ X, const float* __restrict__ W,
    const float* __restrict__ bias, TOUT* __restrict__ out,
    int M, int N, int K) {
  int64_t idx = (int64_t)blockIdx.x * 256 + threadIdx.x;
  if (idx >= (int64_t)M * N) return;
  int m = (int)(idx / N), n = (int)(idx % N);
  const TX* xr = X + (int64_t)m * K;
  const float* wr = W + (int64_t)n * K;
  float acc = 0.f;
  for (int kk = 0; kk < K; ++kk) acc += (float)xr[kk] * wr[kk];
  out[idx] = (TOUT)(acc + bias[n]);
}

// ---------------------------------------------------------------------------
// NAIVE k_r + RoPE, fp32 out. One thread per (row, r); row = token*16 + h,
// token = b*1024 + s. k_r[row][r] = dot(k[row], Wkr[r]) + b[r], then
// rope: out[r] = x[r]*cos(s*f[r%32]) + (r<32 ? -x[r+32] : x[r-32])*sin(...).
// ---------------------------------------------------------------------------
__global__ __launch_bounds__(256) void kr_rope_naive(
    const bf16* __restrict__ kmat, const float* __restrict__ Wkr,
    const float* __restrict__ bkr, float* __restrict__ krout) {
  int idx = blockIdx.x * 256 + threadIdx.x;  // 32768*64 = 2097152
  if (idx >= 32768 * 64) return;
  int row = idx >> 6, r = idx & 63;
  int s = (row >> 4) & 1023;  // position within sequence
  int rp = (r + 32) & 63;     // rotate-half partner column
  const bf16* krow = kmat + (int64_t)row * 128;
  float xr = bkr[r], xp = bkr[rp];
  for (int d = 0; d < 128; ++d) {
    float kv = (float)krow[d];
    xr += kv * Wkr[r * 128 + d];
    xp += kv * Wkr[rp * 128 + d];
  }
  // freqs[j] = 10000^(-j/32); log2(10000)/32 = 0.41524101186092034
  float fr = exp2f(-(float)(r & 31) * 0.41524101186092034f);
  float ang = (float)s * fr;
  float o = xr * cosf(ang) + ((r < 32) ? -xp : xp) * sinf(ang);
  krout[idx] = o;
}

// ---------------------------------------------------------------------------
// NAIVE attention: one block per (b, h, qi). Plain softmax (safe: |s*scale|
// small). q,k,v are bf16 [token][h*128+d]. attn out bf16 same layout.
// ---------------------------------------------------------------------------
__global__ __launch_bounds__(256) void attn_naive(const bf16* __restrict__ q,
                                                  const bf16* __restrict__ k,
                                                  const bf16* __restrict__ v,
                                                  bf16* __restrict__ attn) {
  const int blk = blockIdx.x;       // (b*16+h)*1024 + qi
  const int qi = blk & 1023;
  const int bh = blk >> 10;
  const int b = bh >> 4, h = bh & 15;
  const int t = threadIdx.x;
  __shared__ float sc[1024];
  __shared__ float red[256];
  const float scale = 0.08838834764831845f;  // 1/sqrt(128)

  const bf16* qrow  = q + ((int64_t)(b * 1024 + qi)) * 2048 + h * 128;
  const bf16* kbase = k + ((int64_t)(b * 1024)) * 2048 + h * 128;
  const bf16* vbase = v + ((int64_t)(b * 1024)) * 2048 + h * 128;

  for (int kk = t; kk < 1024; kk += 256) {
    const bf16* krow = kbase + (int64_t)kk * 2048;
    float acc = 0.f;
    for (int d = 0; d < 128; ++d) acc += (float)qrow[d] * (float)krow[d];
    sc[kk] = __expf(acc * scale);
  }
  __syncthreads();

  float ls = 0.f;
  for (int kk = t; kk < 1024; kk += 256) ls += sc[kk];
  red[t] = ls;
  __syncthreads();
  for (int o = 128; o >= 1; o >>= 1) {
    if (t < o) red[t] += red[t + o];
    __syncthreads();
  }
  const float tot = red[0];
  __syncthreads();  // red about to be reused

  const int d = t & 127, half = t >> 7;
  float acc = 0.f;
  for (int kk = half * 512; kk < half * 512 + 512; ++kk)
    acc += sc[kk] * (float)vbase[(int64_t)kk * 2048 + d];
  red[t] = acc;
  __syncthreads();
  if (half == 0) {
    float r = (red[t] + red[t + 128]) / tot;
    attn[((int64_t)(b * 1024 + qi)) * 2048 + h * 128 + d] = (bf16)r;
  }
}

// ---------------------------------------------------------------------------
extern "C" void kernel_launch(void* const* d_in, const int* in_sizes, int n_in,
                              void* d_out, int out_size, void* d_ws, size_t ws_size,
                              hipStream_t stream) {
  // Inputs fp32 (established round 4: bf16 interpretation NaNs, fp32 doesn't).
  const float* hidden = (const float*)d_in[0];
  const float* Wdkv = (const float*)d_in[1];
  const float* bdkv = (const float*)d_in[2];
  const float* Wuk  = (const float*)d_in[3];
  const float* buk  = (const float*)d_in[4];
  const float* Wuv  = (const float*)d_in[5];
  const float* buv  = (const float*)d_in[6];
  const float* Wkr  = (const float*)d_in[7];
  const float* bkr  = (const float*)d_in[8];
  const float* Wdq  = (const float*)d_in[9];
  const float* bdq  = (const float*)d_in[10];
  const float* Wuq  = (const float*)d_in[11];
  const float* buq  = (const float*)d_in[12];
  // d_in[13], d_in[14] (W_QR_w/b): dead code in the reference.
  const float* Wo   = (const float*)d_in[15];
  const float* bo   = (const float*)d_in[16];

  // OUTPUTS ARE FP32 (round-6 deduction). Flat element offsets:
  float* out0 = (float*)d_out;          // [2048][2048] output
  float* c_kv = out0 + 4194304;         // [2048][512]
  float* k_r  = out0 + 5242880;         // [32768][64] = (b,s,H,R)

  // ws: bf16 intermediates. cq 3.1M + k 4.19M + v 4.19M + attn 4.19M
  //   = 15.73M bf16 = 31.5 MB.
  bf16* cq   = (bf16*)d_ws;             // [2048][1536]
  bf16* kx   = cq + 3145728;            // [2048][2048]
  bf16* vx   = kx + 4194304;            // [2048][2048]
  bf16* attn = vx + 4194304;            // [2048][2048]
  // q stashed as bf16 in the out0 region (8.4 MB of its 16.8 MB); the final
  // fp32 GEMM overwrites the whole region afterwards.
  bf16* qx   = (bf16*)out0;             // [2048][2048]

  // c_kv (fp32, output 1)
  gemm_naive<float, float><<<4096, 256, 0, stream>>>(hidden, Wdkv, bdkv, c_kv, 2048, 512, 2048);
  // c_q (bf16 scratch)
  gemm_naive<float, bf16><<<12288, 256, 0, stream>>>(hidden, Wdq, bdq, cq, 2048, 1536, 2048);
  // k, v from fp32 c_kv
  gemm_naive<float, bf16><<<16384, 256, 0, stream>>>(c_kv, Wuk, buk, kx, 2048, 2048, 512);
  gemm_naive<float, bf16><<<16384, 256, 0, stream>>>(c_kv, Wuv, buv, vx, 2048, 2048, 512);
  // q from c_q -> stash in out0 region
  gemm_naive<bf16, bf16><<<16384, 256, 0, stream>>>(cq, Wuq, buq, qx, 2048, 2048, 1536);
  // k_r (fp32, output 2)
  kr_rope_naive<<<8192, 256, 0, stream>>>(kx, Wkr, bkr, k_r);
  // attention
  attn_naive<<<32768, 256, 0, stream>>>(qx, kx, vx, attn);
  // final projection (fp32, output 0) — overwrites the q stash
  gemm_naive<bf16, float><<<16384, 256, 0, stream>>>(attn, Wo, bo, out0, 2048, 2048, 2048);
}

// Round 8
// 570.307 us; speedup vs baseline: 177.0407x; 177.0407x over previous
//
#include <hip/hip_runtime.h>
#include <cstdint>

typedef __bf16 bf16;
typedef __attribute__((ext_vector_type(8))) __bf16 bf16x8;
typedef __attribute__((ext_vector_type(4))) float f32x4;

#define MFMA16(a, b, c) __builtin_amdgcn_mfma_f32_16x16x32_bf16(a, b, c, 0, 0, 0)

// load 8 consecutive elements as bf16x8 (fp32 source converts on the fly)
__device__ __forceinline__ bf16x8 load8(const bf16* p) { return *(const bf16x8*)p; }
__device__ __forceinline__ bf16x8 load8(const float* p) {
  f32x4 a = *(const f32x4*)p;
  f32x4 b = *(const f32x4*)(p + 4);
  bf16x8 r;
  r[0] = (bf16)a[0]; r[1] = (bf16)a[1]; r[2] = (bf16)a[2]; r[3] = (bf16)a[3];
  r[4] = (bf16)b[0]; r[5] = (bf16)b[1]; r[6] = (bf16)b[2]; r[7] = (bf16)b[3];
  return r;
}

// ---------------------------------------------------------------------------
// C = X @ W^T + bias, fp32 accum, TOUT out. X:[M,K] (TX), W:[N,K] fp32,
// bias fp32. 128x128 tile, BK=32, 4 waves of 64x64 (m97/m93 structure).
// ---------------------------------------------------------------------------
template <typename TX, typename TOUT>
__global__ __launch_bounds__(256) void gemm_bt(
    const TX* __restrict__ X, const float* __restrict__ W,
    const float* __restrict__ bias, TOUT* __restrict__ out,
    int M, int N, int K) {
  __shared__ __align__(16) bf16 As[128 * 32];
  __shared__ __align__(16) bf16 Bs[128 * 32];
  const int t = threadIdx.x;
  const int lane = t & 63, w = t >> 6;
  const int quad = lane >> 4, l15 = lane & 15;
  const int bm = blockIdx.y * 128, bn = blockIdx.x * 128;
  const int wm = (w >> 1) * 64, wn = (w & 1) * 64;

  f32x4 acc[4][4] = {};

  // staging: thread t covers row t/4 (and +64), cols (t%4)*8 .. +7
  const int srow = t >> 2;
  const int scol = (t & 3) * 8;
  const TX* Xp = X + (int64_t)(bm + srow) * K + scol;
  const float* Wp = W + (int64_t)(bn + srow) * K + scol;
  bf16* dstA0 = As + srow * 32 + scol;
  bf16* dstA1 = As + (srow + 64) * 32 + scol;
  bf16* dstB0 = Bs + srow * 32 + scol;
  bf16* dstB1 = Bs + (srow + 64) * 32 + scol;

  for (int k0 = 0; k0 < K; k0 += 32) {
    bf16x8 va0 = load8(Xp + k0);
    bf16x8 va1 = load8(Xp + (int64_t)64 * K + k0);
    bf16x8 vb0 = load8(Wp + k0);
    bf16x8 vb1 = load8(Wp + (int64_t)64 * K + k0);
    *(bf16x8*)dstA0 = va0;
    *(bf16x8*)dstA1 = va1;
    *(bf16x8*)dstB0 = vb0;
    *(bf16x8*)dstB1 = vb1;
    __syncthreads();  // staging visible to all waves

    bf16x8 a[4], b[4];
#pragma unroll
    for (int mt = 0; mt < 4; ++mt)
      a[mt] = *(const bf16x8*)(As + (wm + mt * 16 + l15) * 32 + quad * 8);
#pragma unroll
    for (int nt = 0; nt < 4; ++nt)
      b[nt] = *(const bf16x8*)(Bs + (wn + nt * 16 + l15) * 32 + quad * 8);
#pragma unroll
    for (int mt = 0; mt < 4; ++mt)
#pragma unroll
      for (int nt = 0; nt < 4; ++nt)
        acc[mt][nt] = MFMA16(a[mt], b[nt], acc[mt][nt]);
    __syncthreads();  // all reads done before next staging
  }

  float bv[4];
#pragma unroll
  for (int nt = 0; nt < 4; ++nt)
    bv[nt] = bias[bn + wn + nt * 16 + l15];
#pragma unroll
  for (int mt = 0; mt < 4; ++mt)
#pragma unroll
    for (int nt = 0; nt < 4; ++nt)
#pragma unroll
      for (int r = 0; r < 4; ++r) {
        // C/D layout (m89/m91 verified): row = quad*4+r, col = lane&15
        int64_t m = bm + wm + mt * 16 + quad * 4 + r;
        int64_t n = bn + wn + nt * 16 + l15;
        out[m * N + n] = (TOUT)(acc[mt][nt][r] + bv[nt]);
      }
}

// ---------------------------------------------------------------------------
// k_r = rope(k_flat @ W_KR^T + b_KR), fp32 out. k_flat: [32768][128] bf16
// (rows = token*16 + h). Block: 64 rows (4 waves x 16). 16 MFMAs per wave.
// ---------------------------------------------------------------------------
__global__ __launch_bounds__(256) void kr_rope(const bf16* __restrict__ kmat,
                                               const float* __restrict__ Wkr,
                                               const float* __restrict__ bkr,
                                               float* __restrict__ krout) {
  const int t = threadIdx.x;
  const int lane = t & 63, w = t >> 6;
  const int quad = lane >> 4, l15 = lane & 15;
  const int row0 = blockIdx.x * 64 + w * 16;

  bf16x8 af[4];
#pragma unroll
  for (int ks = 0; ks < 4; ++ks)
    af[ks] = *(const bf16x8*)(kmat + (row0 + l15) * 128 + ks * 32 + quad * 8);

  f32x4 acc[4] = {};
#pragma unroll
  for (int nt = 0; nt < 4; ++nt)
#pragma unroll
    for (int ks = 0; ks < 4; ++ks) {
      bf16x8 bf_ = load8(Wkr + (nt * 16 + l15) * 128 + ks * 32 + quad * 8);
      acc[nt] = MFMA16(af[ks], bf_, acc[nt]);
    }

  float bv[4], fr[4];
#pragma unroll
  for (int nt = 0; nt < 4; ++nt) {
    bv[nt] = bkr[nt * 16 + l15];
    int j = ((nt & 1) * 16 + l15);  // n mod 32
    // freqs[j] = 10000^(-j/32); log2(10000)/32 = 0.41524101186092034
    fr[nt] = exp2f(-(float)j * 0.41524101186092034f);
  }

#pragma unroll
  for (int r = 0; r < 4; ++r) {
    int row = row0 + quad * 4 + r;   // row = token*16 + h
    int pos = (row >> 4) & 1023;     // s = token mod 1024
    float val[4];
#pragma unroll
    for (int nt = 0; nt < 4; ++nt) val[nt] = acc[nt][r] + bv[nt];
#pragma unroll
    for (int nt = 0; nt < 4; ++nt) {
      int n = nt * 16 + l15;
      float ang = (float)pos * fr[nt];
      float c = cosf(ang), s = sinf(ang);
      float partner = val[nt ^ 2];  // col (n+32)%64 lives in fragment nt^2
      float o = val[nt] * c + ((nt < 2) ? -partner : partner) * s;
      krout[(int64_t)row * 64 + n] = o;
    }
  }
}

// ---------------------------------------------------------------------------
// Attention, plain softmax (exact-safe: |s*scale| small). Grid (16 q-tiles,
// 32 b*h). Block = 4 waves; wave = 16 q-rows x full D=128. K-tiles of 64.
// V staged transposed into LDS. Pads (136/72) kill power-of-2 conflicts.
// ---------------------------------------------------------------------------
__global__ __launch_bounds__(256) void attn_fwd(const bf16* __restrict__ q,
                                                const bf16* __restrict__ k,
                                                const bf16* __restrict__ v,
                                                bf16* __restrict__ attn) {
  const int qt = blockIdx.x, bh = blockIdx.y;
  const int b = bh >> 4, h = bh & 15;
  __shared__ __align__(16) bf16 Kt[64 * 136];   // [key][d], stride 136
  __shared__ __align__(16) bf16 Vt[128 * 72];   // [d][key], stride 72
  __shared__ __align__(16) bf16 Pl[4][16 * 72]; // per-wave P, stride 72

  const int t = threadIdx.x;
  const int lane = t & 63, w = t >> 6;
  const int quad = lane >> 4, l15 = lane & 15;
  const int trow = b * 1024 + qt * 64 + w * 16;  // wave's q-row base (token)
  const float scale = 0.08838834764831845f;      // 1/sqrt(128)

  bf16x8 qf[4];
#pragma unroll
  for (int ks = 0; ks < 4; ++ks)
    qf[ks] = *(const bf16x8*)(q + (int64_t)(trow + l15) * 2048 + h * 128 +
                              ks * 32 + quad * 8);

  f32x4 o[8] = {};
  float lrow[4] = {0.f, 0.f, 0.f, 0.f};

  for (int kt = 0; kt < 16; ++kt) {
    __syncthreads();  // all waves' PV reads of previous tile done
#pragma unroll
    for (int r = 0; r < 4; ++r) {
      int e = (r * 256 + t) * 8;
      int key = e >> 7, dc = e & 127;
      *(bf16x8*)(Kt + key * 136 + dc) =
          *(const bf16x8*)(k + (int64_t)(b * 1024 + kt * 64 + key) * 2048 +
                           h * 128 + dc);
    }
#pragma unroll
    for (int r = 0; r < 4; ++r) {
      int e = (r * 256 + t) * 8;
      int key = e >> 7, d0 = e & 127;
      bf16x8 pk = *(const bf16x8*)(v + (int64_t)(b * 1024 + kt * 64 + key) * 2048 +
                                   h * 128 + d0);
#pragma unroll
      for (int j = 0; j < 8; ++j) Vt[(d0 + j) * 72 + key] = pk[j];
    }
    __syncthreads();  // staging visible

    // S = Q @ K^T  (16 x 64 per wave)
    f32x4 s[4] = {};
#pragma unroll
    for (int nt = 0; nt < 4; ++nt)
#pragma unroll
      for (int ks = 0; ks < 4; ++ks) {
        bf16x8 bfrg = *(const bf16x8*)(Kt + (nt * 16 + l15) * 136 + ks * 32 + quad * 8);
        s[nt] = MFMA16(qf[ks], bfrg, s[nt]);
      }

    // p = exp(s*scale); accumulate row sums; stash P (bf16) for PV.
    float rsum[4] = {0.f, 0.f, 0.f, 0.f};
#pragma unroll
    for (int nt = 0; nt < 4; ++nt)
#pragma unroll
      for (int r = 0; r < 4; ++r) {
        float p = __expf(s[nt][r] * scale);
        rsum[r] += p;
        Pl[w][(quad * 4 + r) * 72 + nt * 16 + l15] = (bf16)p;
      }
#pragma unroll
    for (int r = 0; r < 4; ++r) {
      float ssum = rsum[r];
#pragma unroll
      for (int off = 8; off >= 1; off >>= 1) ssum += __shfl_xor(ssum, off, 64);
      lrow[r] += ssum;
    }

    // O += P @ V  (Pl per-wave; same-wave DS ops execute in order)
#pragma unroll
    for (int ks = 0; ks < 2; ++ks) {
      bf16x8 afrg = *(const bf16x8*)(&Pl[w][l15 * 72 + ks * 32 + quad * 8]);
#pragma unroll
      for (int dt = 0; dt < 8; ++dt) {
        bf16x8 bfrg = *(const bf16x8*)(Vt + (dt * 16 + l15) * 72 + ks * 32 + quad * 8);
        o[dt] = MFMA16(afrg, bfrg, o[dt]);
      }
    }
  }

#pragma unroll
  for (int dt = 0; dt < 8; ++dt)
#pragma unroll
    for (int r = 0; r < 4; ++r) {
      int64_t row = trow + quad * 4 + r;
      int col = h * 128 + dt * 16 + l15;
      attn[row * 2048 + col] = (bf16)(o[dt][r] / lrow[r]);
    }
}

// ---------------------------------------------------------------------------
extern "C" void kernel_launch(void* const* d_in, const int* in_sizes, int n_in,
                              void* d_out, int out_size, void* d_ws, size_t ws_size,
                              hipStream_t stream) {
  const float* hidden = (const float*)d_in[0];
  const float* Wdkv = (const float*)d_in[1];
  const float* bdkv = (const float*)d_in[2];
  const float* Wuk  = (const float*)d_in[3];
  const float* buk  = (const float*)d_in[4];
  const float* Wuv  = (const float*)d_in[5];
  const float* buv  = (const float*)d_in[6];
  const float* Wkr  = (const float*)d_in[7];
  const float* bkr  = (const float*)d_in[8];
  const float* Wdq  = (const float*)d_in[9];
  const float* bdq  = (const float*)d_in[10];
  const float* Wuq  = (const float*)d_in[11];
  const float* buq  = (const float*)d_in[12];
  // d_in[13], d_in[14] (W_QR_w/b): dead code in the reference.
  const float* Wo   = (const float*)d_in[15];
  const float* bo   = (const float*)d_in[16];

  // Outputs fp32 (established round 7).
  float* out0 = (float*)d_out;          // [2048][2048]
  float* c_kv = out0 + 4194304;         // [2048][512]
  float* k_r  = out0 + 5242880;         // [32768][64]

  // ws: bf16 intermediates, 31.5 MB (round 7 proved ws_size >= this).
  bf16* cq   = (bf16*)d_ws;             // [2048][1536]
  bf16* kx   = cq + 3145728;            // [2048][2048]
  bf16* vx   = kx + 4194304;            // [2048][2048]
  bf16* attn = vx + 4194304;            // [2048][2048]
  bf16* qx   = (bf16*)out0;             // q stash in out0 region (overwritten by final GEMM)

  gemm_bt<float, float><<<dim3(4, 16), 256, 0, stream>>>(hidden, Wdkv, bdkv, c_kv, 2048, 512, 2048);
  gemm_bt<float, bf16><<<dim3(12, 16), 256, 0, stream>>>(hidden, Wdq, bdq, cq, 2048, 1536, 2048);
  gemm_bt<float, bf16><<<dim3(16, 16), 256, 0, stream>>>(c_kv, Wuk, buk, kx, 2048, 2048, 512);
  gemm_bt<float, bf16><<<dim3(16, 16), 256, 0, stream>>>(c_kv, Wuv, buv, vx, 2048, 2048, 512);
  gemm_bt<bf16, bf16><<<dim3(16, 16), 256, 0, stream>>>(cq, Wuq, buq, qx, 2048, 2048, 1536);
  kr_rope<<<512, 256, 0, stream>>>(kx, Wkr, bkr, k_r);
  attn_fwd<<<dim3(16, 32), 256, 0, stream>>>(qx, kx, vx, attn);
  gemm_bt<bf16, float><<<dim3(16, 16), 256, 0, stream>>>(attn, Wo, bo, out0, 2048, 2048, 2048);
}

// Round 9
// 532.089 us; speedup vs baseline: 189.7570x; 1.0718x over previous
//
#include <hip/hip_runtime.h>
#include <cstdint>

typedef __bf16 bf16;
typedef __attribute__((ext_vector_type(8))) __bf16 bf16x8;
typedef __attribute__((ext_vector_type(4))) float f32x4;

#define MFMA16(a, b, c) __builtin_amdgcn_mfma_f32_16x16x32_bf16(a, b, c, 0, 0, 0)

// async global->LDS, 16B per lane; LDS dest = wave-uniform base + lane*16.
__device__ __forceinline__ void async16(const bf16* g, bf16* l) {
  __builtin_amdgcn_global_load_lds(
      (const __attribute__((address_space(1))) void*)g,
      (__attribute__((address_space(3))) void*)l, 16, 0, 0);
}

__device__ __forceinline__ bf16x8 load8cvt(const float* p) {
  f32x4 a = *(const f32x4*)p;
  f32x4 b = *(const f32x4*)(p + 4);
  bf16x8 r;
  r[0] = (bf16)a[0]; r[1] = (bf16)a[1]; r[2] = (bf16)a[2]; r[3] = (bf16)a[3];
  r[4] = (bf16)b[0]; r[5] = (bf16)b[1]; r[6] = (bf16)b[2]; r[7] = (bf16)b[3];
  return r;
}

// ---------------------------------------------------------------------------
// fp32 -> bf16 elementwise convert (8 elems/thread)
// ---------------------------------------------------------------------------
__global__ __launch_bounds__(256) void cvt_f32_bf16(const float* __restrict__ src,
                                                    bf16* __restrict__ dst, int n) {
  int i = (blockIdx.x * 256 + threadIdx.x) * 8;
  if (i >= n) return;
  *(bf16x8*)(dst + i) = load8cvt(src + i);
}

// ---------------------------------------------------------------------------
// C = X @ W^T + bias. X bf16 [M,K] (A staged via global_load_lds x16),
// W fp32 [N,K] (staged with convert), bias fp32. 128x128 tile, BK=32,
// 4 waves of 64x64 (m97 structure). DUAL: also store bf16 copy to out2.
// ---------------------------------------------------------------------------
template <typename TOUT, bool DUAL>
__global__ __launch_bounds__(256) void gemm_bt(
    const bf16* __restrict__ X, const float* __restrict__ W,
    const float* __restrict__ bias, TOUT* __restrict__ out,
    bf16* __restrict__ out2, int M, int N, int K) {
  __shared__ __align__(16) bf16 As[128 * 32];
  __shared__ __align__(16) bf16 Bs[128 * 32];
  const int t = threadIdx.x;
  const int lane = t & 63, w = t >> 6;
  const int quad = lane >> 4, l15 = lane & 15;
  const int bm = blockIdx.y * 128, bn = blockIdx.x * 128;
  const int wm = (w >> 1) * 64, wn = (w & 1) * 64;

  f32x4 acc[4][4] = {};

  // staging map: thread t covers row t/4 (and +64), cols (t%4)*8..+7
  const int srow = t >> 2;
  const int scol = (t & 3) * 8;
  const bf16* Xp = X + (int64_t)(bm + srow) * K + scol;  // lane-resolved A src
  const float* Wp = W + (int64_t)(bn + srow) * K + scol;
  bf16* ldsA0 = As + w * 512;         // wave-uniform LDS bases (16 rows/wave)
  bf16* ldsA1 = As + 2048 + w * 512;
  bf16* dstB0 = Bs + srow * 32 + scol;
  bf16* dstB1 = Bs + (srow + 64) * 32 + scol;

  for (int k0 = 0; k0 < K; k0 += 32) {
    async16(Xp + k0, ldsA0);
    async16(Xp + (int64_t)64 * K + k0, ldsA1);
    bf16x8 vb0 = load8cvt(Wp + k0);
    bf16x8 vb1 = load8cvt(Wp + (int64_t)64 * K + k0);
    *(bf16x8*)dstB0 = vb0;
    *(bf16x8*)dstB1 = vb1;
    __syncthreads();  // drains vmcnt+lgkm: all staging visible

    bf16x8 a[4], b[4];
#pragma unroll
    for (int mt = 0; mt < 4; ++mt)
      a[mt] = *(const bf16x8*)(As + (wm + mt * 16 + l15) * 32 + quad * 8);
#pragma unroll
    for (int nt = 0; nt < 4; ++nt)
      b[nt] = *(const bf16x8*)(Bs + (wn + nt * 16 + l15) * 32 + quad * 8);
#pragma unroll
    for (int mt = 0; mt < 4; ++mt)
#pragma unroll
      for (int nt = 0; nt < 4; ++nt)
        acc[mt][nt] = MFMA16(a[mt], b[nt], acc[mt][nt]);
    __syncthreads();  // all reads done before next staging
  }

  float bv[4];
#pragma unroll
  for (int nt = 0; nt < 4; ++nt)
    bv[nt] = bias[bn + wn + nt * 16 + l15];
#pragma unroll
  for (int mt = 0; mt < 4; ++mt)
#pragma unroll
    for (int nt = 0; nt < 4; ++nt)
#pragma unroll
      for (int r = 0; r < 4; ++r) {
        // C/D layout (m89/m91 verified): row = quad*4+r, col = lane&15
        int64_t m = bm + wm + mt * 16 + quad * 4 + r;
        int64_t n = bn + wn + nt * 16 + l15;
        float v = acc[mt][nt][r] + bv[nt];
        out[m * N + n] = (TOUT)v;
        if (DUAL) out2[m * N + n] = (bf16)v;
      }
}

// ---------------------------------------------------------------------------
// k_r = rope(k_flat @ W_KR^T + b_KR), fp32 out. k_flat: [32768][128] bf16.
// ---------------------------------------------------------------------------
__global__ __launch_bounds__(256) void kr_rope(const bf16* __restrict__ kmat,
                                               const float* __restrict__ Wkr,
                                               const float* __restrict__ bkr,
                                               float* __restrict__ krout) {
  const int t = threadIdx.x;
  const int lane = t & 63, w = t >> 6;
  const int quad = lane >> 4, l15 = lane & 15;
  const int row0 = blockIdx.x * 64 + w * 16;

  bf16x8 af[4];
#pragma unroll
  for (int ks = 0; ks < 4; ++ks)
    af[ks] = *(const bf16x8*)(kmat + (row0 + l15) * 128 + ks * 32 + quad * 8);

  f32x4 acc[4] = {};
#pragma unroll
  for (int nt = 0; nt < 4; ++nt)
#pragma unroll
    for (int ks = 0; ks < 4; ++ks) {
      bf16x8 bf_ = load8cvt(Wkr + (nt * 16 + l15) * 128 + ks * 32 + quad * 8);
      acc[nt] = MFMA16(af[ks], bf_, acc[nt]);
    }

  float bv[4], fr[4];
#pragma unroll
  for (int nt = 0; nt < 4; ++nt) {
    bv[nt] = bkr[nt * 16 + l15];
    int j = ((nt & 1) * 16 + l15);  // n mod 32
    fr[nt] = exp2f(-(float)j * 0.41524101186092034f);  // 10000^(-j/32)
  }

#pragma unroll
  for (int r = 0; r < 4; ++r) {
    int row = row0 + quad * 4 + r;   // row = token*16 + h
    int pos = (row >> 4) & 1023;     // s = token mod 1024
    float val[4];
#pragma unroll
    for (int nt = 0; nt < 4; ++nt) val[nt] = acc[nt][r] + bv[nt];
#pragma unroll
    for (int nt = 0; nt < 4; ++nt) {
      int n = nt * 16 + l15;
      float ang = (float)pos * fr[nt];
      float c = cosf(ang), s = sinf(ang);
      float partner = val[nt ^ 2];  // col (n+32)%64 lives in fragment nt^2
      float o = val[nt] * c + ((nt < 2) ? -partner : partner) * s;
      krout[(int64_t)row * 64 + n] = o;
    }
  }
}

// ---------------------------------------------------------------------------
// Attention, plain softmax. Grid (16 q-tiles, 32 b*h), 4 waves/block.
// Vt uses XOR-swizzled key-blocks: elem(d,key) = d*72 + ((key>>3 ^ ((d>>3)&7))<<3)
// + (key&7). Store lanes then land on 8 distinct banks x2 (free) instead of the
// old 16-way same-bank pileup (3.6e7 conflict cycles in round 8).
// ---------------------------------------------------------------------------
__global__ __launch_bounds__(256) void attn_fwd(const bf16* __restrict__ q,
                                                const bf16* __restrict__ k,
                                                const bf16* __restrict__ v,
                                                bf16* __restrict__ attn) {
  const int qt = blockIdx.x, bh = blockIdx.y;
  const int b = bh >> 4, h = bh & 15;
  __shared__ __align__(16) bf16 Kt[64 * 136];   // [key][d], stride 136
  __shared__ __align__(16) bf16 Vt[128 * 72];   // [d][key-swizzled], stride 72
  __shared__ __align__(16) bf16 Pl[4][16 * 72]; // per-wave P, stride 72

  const int t = threadIdx.x;
  const int lane = t & 63, w = t >> 6;
  const int quad = lane >> 4, l15 = lane & 15;
  const int trow = b * 1024 + qt * 64 + w * 16;
  const float scale = 0.08838834764831845f;      // 1/sqrt(128)

  bf16x8 qf[4];
#pragma unroll
  for (int ks = 0; ks < 4; ++ks)
    qf[ks] = *(const bf16x8*)(q + (int64_t)(trow + l15) * 2048 + h * 128 +
                              ks * 32 + quad * 8);

  f32x4 o[8] = {};
  float lrow[4] = {0.f, 0.f, 0.f, 0.f};

  for (int kt = 0; kt < 16; ++kt) {
    __syncthreads();
#pragma unroll
    for (int r = 0; r < 4; ++r) {
      int e = (r * 256 + t) * 8;
      int key = e >> 7, dc = e & 127;
      *(bf16x8*)(Kt + key * 136 + dc) =
          *(const bf16x8*)(k + (int64_t)(b * 1024 + kt * 64 + key) * 2048 +
                           h * 128 + dc);
    }
    // V tile transposed with XOR-swizzled key-blocks
#pragma unroll
    for (int r = 0; r < 4; ++r) {
      int e = (r * 256 + t) * 8;
      int key = e >> 7, d0 = e & 127;        // d0 multiple of 8
      bf16x8 pk = *(const bf16x8*)(v + (int64_t)(b * 1024 + kt * 64 + key) * 2048 +
                                   h * 128 + d0);
      int col = (((key >> 3) ^ ((d0 >> 3) & 7)) << 3) + (key & 7);
#pragma unroll
      for (int j = 0; j < 8; ++j) Vt[(d0 + j) * 72 + col] = pk[j];
    }
    __syncthreads();

    // S = Q @ K^T  (16 x 64 per wave)
    f32x4 s[4] = {};
#pragma unroll
    for (int nt = 0; nt < 4; ++nt)
#pragma unroll
      for (int ks = 0; ks < 4; ++ks) {
        bf16x8 bfrg = *(const bf16x8*)(Kt + (nt * 16 + l15) * 136 + ks * 32 + quad * 8);
        s[nt] = MFMA16(qf[ks], bfrg, s[nt]);
      }

    // p = exp(s*scale); row sums; stash P for PV
    float rsum[4] = {0.f, 0.f, 0.f, 0.f};
#pragma unroll
    for (int nt = 0; nt < 4; ++nt)
#pragma unroll
      for (int r = 0; r < 4; ++r) {
        float p = __expf(s[nt][r] * scale);
        rsum[r] += p;
        Pl[w][(quad * 4 + r) * 72 + nt * 16 + l15] = (bf16)p;
      }
#pragma unroll
    for (int r = 0; r < 4; ++r) {
      float ssum = rsum[r];
#pragma unroll
      for (int off = 8; off >= 1; off >>= 1) ssum += __shfl_xor(ssum, off, 64);
      lrow[r] += ssum;
    }

    // O += P @ V  (B-fragment: 8 consecutive keys at fixed d -> one swizzled block)
#pragma unroll
    for (int ks = 0; ks < 2; ++ks) {
      bf16x8 afrg = *(const bf16x8*)(&Pl[w][l15 * 72 + ks * 32 + quad * 8]);
#pragma unroll
      for (int dt = 0; dt < 8; ++dt) {
        int d = dt * 16 + l15;
        int kb = ((ks * 4 + quad) ^ ((d >> 3) & 7)) << 3;
        bf16x8 bfrg = *(const bf16x8*)(Vt + d * 72 + kb);
        o[dt] = MFMA16(afrg, bfrg, o[dt]);
      }
    }
  }

#pragma unroll
  for (int dt = 0; dt < 8; ++dt)
#pragma unroll
    for (int r = 0; r < 4; ++r) {
      int64_t row = trow + quad * 4 + r;
      int col = h * 128 + dt * 16 + l15;
      attn[row * 2048 + col] = (bf16)(o[dt][r] / lrow[r]);
    }
}

// ---------------------------------------------------------------------------
extern "C" void kernel_launch(void* const* d_in, const int* in_sizes, int n_in,
                              void* d_out, int out_size, void* d_ws, size_t ws_size,
                              hipStream_t stream) {
  const float* hidden = (const float*)d_in[0];
  const float* Wdkv = (const float*)d_in[1];
  const float* bdkv = (const float*)d_in[2];
  const float* Wuk  = (const float*)d_in[3];
  const float* buk  = (const float*)d_in[4];
  const float* Wuv  = (const float*)d_in[5];
  const float* buv  = (const float*)d_in[6];
  const float* Wkr  = (const float*)d_in[7];
  const float* bkr  = (const float*)d_in[8];
  const float* Wdq  = (const float*)d_in[9];
  const float* bdq  = (const float*)d_in[10];
  const float* Wuq  = (const float*)d_in[11];
  const float* buq  = (const float*)d_in[12];
  // d_in[13], d_in[14] (W_QR_w/b): dead code in the reference.
  const float* Wo   = (const float*)d_in[15];
  const float* bo   = (const float*)d_in[16];

  // Outputs fp32.
  float* out0 = (float*)d_out;          // [2048][2048]
  float* c_kv = out0 + 4194304;         // [2048][512]
  float* k_r  = out0 + 5242880;         // [32768][64]

  // out0 region reused for bf16 stashes until the final GEMM overwrites it:
  bf16* qx = (bf16*)out0;               // [2048][2048] bf16, bytes [0, 8.4MB)
  bf16* hb = qx + 4194304;              // hidden bf16,      bytes [8.4, 16.8MB)

  // ws (bf16 elem offsets), 27.3 MB total:
  bf16* region0 = (bf16*)d_ws;          // cq [2048][1536] then attn [2048][2048]
  bf16* kx      = region0 + 4194304;    // [2048][2048]
  bf16* vx      = kx + 4194304;         // [2048][2048]
  bf16* ckv_bf  = vx + 4194304;         // [2048][512]
  bf16* cq   = region0;
  bf16* attn = region0;

  cvt_f32_bf16<<<2048, 256, 0, stream>>>(hidden, hb, 4194304);
  gemm_bt<float, true><<<dim3(4, 16), 256, 0, stream>>>(hb, Wdkv, bdkv, c_kv, ckv_bf, 2048, 512, 2048);
  gemm_bt<bf16, false><<<dim3(12, 16), 256, 0, stream>>>(hb, Wdq, bdq, cq, nullptr, 2048, 1536, 2048);
  gemm_bt<bf16, false><<<dim3(16, 16), 256, 0, stream>>>(ckv_bf, Wuk, buk, kx, nullptr, 2048, 2048, 512);
  gemm_bt<bf16, false><<<dim3(16, 16), 256, 0, stream>>>(ckv_bf, Wuv, buv, vx, nullptr, 2048, 2048, 512);
  gemm_bt<bf16, false><<<dim3(16, 16), 256, 0, stream>>>(cq, Wuq, buq, qx, nullptr, 2048, 2048, 1536);
  kr_rope<<<512, 256, 0, stream>>>(kx, Wkr, bkr, k_r);
  attn_fwd<<<dim3(16, 32), 256, 0, stream>>>(qx, kx, vx, attn);
  gemm_bt<float, false><<<dim3(16, 16), 256, 0, stream>>>(attn, Wo, bo, out0, nullptr, 2048, 2048, 2048);
}